// Round 1
// baseline (243.644 us; speedup 1.0000x reference)
//
#include <hip/hip_runtime.h>

#define N_NODES 32768
#define N_EDGES 16384
#define DEG 4
#define KPE 8
#define DIM 128
#define EDIM 64

typedef float f32x4 __attribute__((ext_vector_type(4)));
typedef __bf16 bf16x8 __attribute__((ext_vector_type(8)));
typedef unsigned short u16x8 __attribute__((ext_vector_type(8)));

static __device__ __forceinline__ unsigned short f2bf(float f) {
  union { float f; unsigned int u; } v; v.f = f;
  unsigned int r = (v.u + 0x7FFFu + ((v.u >> 16) & 1u)) >> 16;
  return (unsigned short)r;
}
static __device__ __forceinline__ float bflo(unsigned int v) {
  union { unsigned int u; float f; } x; x.u = v << 16; return x.f;
}
static __device__ __forceinline__ float bfhi(unsigned int v) {
  union { unsigned int u; float f; } x; x.u = v & 0xffff0000u; return x.f;
}

// ---------------- weight combine: CW=[0.25*Wq@Wlin; Wk@Wlin; Wv@Wlin] (384x128),
// CWE = Wk@Wedge (128x64), Wob = bf16(Wo) ----------------
__global__ __launch_bounds__(256) void wprep_kernel(
    const float* __restrict__ Wq, const float* __restrict__ Wk,
    const float* __restrict__ Wv, const float* __restrict__ Wlin,
    const float* __restrict__ Wedge, const float* __restrict__ Wo,
    unsigned short* __restrict__ CW, unsigned short* __restrict__ CWE,
    unsigned short* __restrict__ Wob)
{
  int id = blockIdx.x * 256 + threadIdx.x;
  if (id < 384 * 128) {
    int j = id >> 7, i = id & 127;
    const float* wrow; float scale = 1.0f;
    if (j < 128)      { wrow = Wq + j * 128; scale = 0.25f; }
    else if (j < 256) { wrow = Wk + (j - 128) * 128; }
    else              { wrow = Wv + (j - 256) * 128; }
    float s = 0.f;
    for (int m = 0; m < 128; ++m) s += wrow[m] * Wlin[m * 128 + i];
    CW[id] = f2bf(s * scale);
  } else if (id < 384 * 128 + 128 * 64) {
    int id2 = id - 384 * 128; int j = id2 >> 6, t = id2 & 63;
    float s = 0.f;
    for (int m = 0; m < 128; ++m) s += Wk[j * 128 + m] * Wedge[m * 64 + t];
    CWE[id2] = f2bf(s);
  } else if (id < 384 * 128 + 128 * 64 + 128 * 128) {
    int id3 = id - (384 * 128 + 128 * 64);
    Wob[id3] = f2bf(Wo[id3]);
  }
}

// ---------------- G1: x[N,128] @ CW[384,128]^T -> qb / WhKb / WhVb (bf16) ------
__global__ __launch_bounds__(256) void g1_kernel(
    const float* __restrict__ x, const unsigned short* __restrict__ CW,
    const float* __restrict__ bq, const float* __restrict__ bv,
    unsigned short* __restrict__ qb, unsigned short* __restrict__ Kb,
    unsigned short* __restrict__ Vb)
{
  const int wave = threadIdx.x >> 6, lane = threadIdx.x & 63;
  const int r16 = lane & 15, quad = lane >> 4;
  const int m0 = blockIdx.x * 64 + wave * 16;
  const int n0 = blockIdx.y * 64;

  f32x4 acc[4];
  const f32x4 z = {0.f, 0.f, 0.f, 0.f};
  acc[0] = z; acc[1] = z; acc[2] = z; acc[3] = z;

  const float* arow = x + (size_t)(m0 + r16) * DIM + quad * 8;
  #pragma unroll
  for (int kk = 0; kk < 4; ++kk) {
    float4 a0 = *(const float4*)(arow + kk * 32);
    float4 a1 = *(const float4*)(arow + kk * 32 + 4);
    u16x8 au;
    au[0] = f2bf(a0.x); au[1] = f2bf(a0.y); au[2] = f2bf(a0.z); au[3] = f2bf(a0.w);
    au[4] = f2bf(a1.x); au[5] = f2bf(a1.y); au[6] = f2bf(a1.z); au[7] = f2bf(a1.w);
    bf16x8 av = __builtin_bit_cast(bf16x8, au);
    #pragma unroll
    for (int s = 0; s < 4; ++s) {
      u16x8 bu = *(const u16x8*)(CW + (size_t)(n0 + s * 16 + r16) * DIM + kk * 32 + quad * 8);
      acc[s] = __builtin_amdgcn_mfma_f32_16x16x32_bf16(
          av, __builtin_bit_cast(bf16x8, bu), acc[s], 0, 0, 0);
    }
  }

  const int arr = blockIdx.y >> 1;          // 0:q 1:K 2:V
  const int colbase = (blockIdx.y & 1) * 64;
  unsigned short* dst = arr == 0 ? qb : (arr == 1 ? Kb : Vb);
  #pragma unroll
  for (int s = 0; s < 4; ++s) {
    int j = colbase + s * 16 + r16;
    float bias = arr == 0 ? 0.25f * bq[j] : (arr == 2 ? bv[j] : 0.f);
    #pragma unroll
    for (int r = 0; r < 4; ++r) {
      int m = m0 + quad * 4 + r;
      dst[(size_t)m * DIM + j] = f2bf(acc[s][r] + bias);
    }
  }
}

// ---------------- G2: edge_attr[E,64] @ CWE[128,64]^T + bk -> WeKb (bf16) ------
__global__ __launch_bounds__(256) void g2_kernel(
    const float* __restrict__ ea, const unsigned short* __restrict__ CWE,
    const float* __restrict__ bk, unsigned short* __restrict__ WeKb)
{
  const int wave = threadIdx.x >> 6, lane = threadIdx.x & 63;
  const int r16 = lane & 15, quad = lane >> 4;
  const int m0 = blockIdx.x * 64 + wave * 16;
  const int n0 = blockIdx.y * 64;

  f32x4 acc[4];
  const f32x4 z = {0.f, 0.f, 0.f, 0.f};
  acc[0] = z; acc[1] = z; acc[2] = z; acc[3] = z;

  const float* arow = ea + (size_t)(m0 + r16) * EDIM + quad * 8;
  #pragma unroll
  for (int kk = 0; kk < 2; ++kk) {
    float4 a0 = *(const float4*)(arow + kk * 32);
    float4 a1 = *(const float4*)(arow + kk * 32 + 4);
    u16x8 au;
    au[0] = f2bf(a0.x); au[1] = f2bf(a0.y); au[2] = f2bf(a0.z); au[3] = f2bf(a0.w);
    au[4] = f2bf(a1.x); au[5] = f2bf(a1.y); au[6] = f2bf(a1.z); au[7] = f2bf(a1.w);
    bf16x8 av = __builtin_bit_cast(bf16x8, au);
    #pragma unroll
    for (int s = 0; s < 4; ++s) {
      u16x8 bu = *(const u16x8*)(CWE + (size_t)(n0 + s * 16 + r16) * EDIM + kk * 32 + quad * 8);
      acc[s] = __builtin_amdgcn_mfma_f32_16x16x32_bf16(
          av, __builtin_bit_cast(bf16x8, bu), acc[s], 0, 0, 0);
    }
  }

  #pragma unroll
  for (int s = 0; s < 4; ++s) {
    int j = n0 + s * 16 + r16;
    float bias = bk[j];
    #pragma unroll
    for (int r = 0; r < 4; ++r) {
      int m = m0 + quad * 4 + r;
      WeKb[(size_t)m * DIM + j] = f2bf(acc[s][r] + bias);
    }
  }
}

// ---------------- G3: per-node attention (1 wave = 1 node) ----------------
// scores: lane=(l, half) computes 4 full head-dots over its 64-dim slice.
// softmax: shuffle-reduce within 32-lane half-group; p -> LDS (stride 33).
// ctx: lane=dim-pair; each key's V-row is one coalesced 256B wave read.
__global__ __launch_bounds__(256) void attn_kernel(
    const unsigned short* __restrict__ qb, const unsigned short* __restrict__ Kb,
    const unsigned short* __restrict__ Vb, const unsigned short* __restrict__ WeKb,
    const int* __restrict__ nedges, const int* __restrict__ enodes,
    unsigned short* __restrict__ ctxb)
{
  __shared__ float ldsP[4][264];
  __shared__ int ldsU[4][32];
  const int wave = threadIdx.x >> 6, lane = threadIdx.x & 63;
  const int n = blockIdx.x * 4 + wave;
  const int l = lane & 31, half = lane >> 5;

  const int e = nedges[n * DEG + (l >> 3)];
  const int u = enodes[e * KPE + (l & 7)];
  if (half == 0) ldsU[wave][l] = u;

  const uint4* qp = (const uint4*)(qb + (size_t)n * DIM + half * 64);
  const uint4* kp = (const uint4*)(Kb + (size_t)u * DIM + half * 64);
  const uint4* ep = (const uint4*)(WeKb + (size_t)e * DIM + half * 64);

  float s[4] = {0.f, 0.f, 0.f, 0.f};
  #pragma unroll
  for (int ch = 0; ch < 8; ++ch) {
    uint4 qv = qp[ch], kv = kp[ch], ev = ep[ch];
    const int hi = ch >> 1;
    s[hi] = fmaf(bflo(qv.x), bflo(kv.x) + bflo(ev.x), s[hi]);
    s[hi] = fmaf(bfhi(qv.x), bfhi(kv.x) + bfhi(ev.x), s[hi]);
    s[hi] = fmaf(bflo(qv.y), bflo(kv.y) + bflo(ev.y), s[hi]);
    s[hi] = fmaf(bfhi(qv.y), bfhi(kv.y) + bfhi(ev.y), s[hi]);
    s[hi] = fmaf(bflo(qv.z), bflo(kv.z) + bflo(ev.z), s[hi]);
    s[hi] = fmaf(bfhi(qv.z), bfhi(kv.z) + bfhi(ev.z), s[hi]);
    s[hi] = fmaf(bflo(qv.w), bflo(kv.w) + bflo(ev.w), s[hi]);
    s[hi] = fmaf(bfhi(qv.w), bfhi(kv.w) + bfhi(ev.w), s[hi]);
  }

  #pragma unroll
  for (int hi = 0; hi < 4; ++hi) {
    float vmax = s[hi];
    #pragma unroll
    for (int off = 16; off >= 1; off >>= 1)
      vmax = fmaxf(vmax, __shfl_xor(vmax, off, 32));
    float ex = __expf(s[hi] - vmax);
    float sum = ex;
    #pragma unroll
    for (int off = 16; off >= 1; off >>= 1)
      sum += __shfl_xor(sum, off, 32);
    ldsP[wave][(half * 4 + hi) * 33 + l] = ex / sum;
  }
  __syncthreads();

  const int c0 = lane * 2;
  const int h = lane >> 3;   // head of dims (c0, c0+1)
  float a0 = 0.f, a1 = 0.f;
  #pragma unroll 8
  for (int l2 = 0; l2 < 32; ++l2) {
    float pw = ldsP[wave][h * 33 + l2];
    int uu = ldsU[wave][l2];
    unsigned int vv = *(const unsigned int*)(Vb + (size_t)uu * DIM + c0);
    a0 = fmaf(pw, bflo(vv), a0);
    a1 = fmaf(pw, bfhi(vv), a1);
  }
  unsigned int pk = (unsigned int)f2bf(a0) | ((unsigned int)f2bf(a1) << 16);
  *(unsigned int*)(ctxb + (size_t)n * DIM + c0) = pk;
}

// ---------------- G4: ctx[N,128] @ Wo[128,128]^T + bo, ReLU -> out fp32 -------
__global__ __launch_bounds__(256) void g4_kernel(
    const unsigned short* __restrict__ ctxb, const unsigned short* __restrict__ Wob,
    const float* __restrict__ bo, float* __restrict__ out)
{
  const int wave = threadIdx.x >> 6, lane = threadIdx.x & 63;
  const int r16 = lane & 15, quad = lane >> 4;
  const int m0 = blockIdx.x * 64 + wave * 16;
  const int n0 = blockIdx.y * 64;

  f32x4 acc[4];
  const f32x4 z = {0.f, 0.f, 0.f, 0.f};
  acc[0] = z; acc[1] = z; acc[2] = z; acc[3] = z;

  #pragma unroll
  for (int kk = 0; kk < 4; ++kk) {
    u16x8 au = *(const u16x8*)(ctxb + (size_t)(m0 + r16) * DIM + kk * 32 + quad * 8);
    bf16x8 av = __builtin_bit_cast(bf16x8, au);
    #pragma unroll
    for (int s = 0; s < 4; ++s) {
      u16x8 bu = *(const u16x8*)(Wob + (size_t)(n0 + s * 16 + r16) * DIM + kk * 32 + quad * 8);
      acc[s] = __builtin_amdgcn_mfma_f32_16x16x32_bf16(
          av, __builtin_bit_cast(bf16x8, bu), acc[s], 0, 0, 0);
    }
  }

  #pragma unroll
  for (int s = 0; s < 4; ++s) {
    int j = n0 + s * 16 + r16;
    float bias = bo[j];
    #pragma unroll
    for (int r = 0; r < 4; ++r) {
      int m = m0 + quad * 4 + r;
      float v = acc[s][r] + bias;
      out[(size_t)m * DIM + j] = v > 0.f ? v : 0.f;
    }
  }
}

extern "C" void kernel_launch(void* const* d_in, const int* in_sizes, int n_in,
                              void* d_out, int out_size, void* d_ws, size_t ws_size,
                              hipStream_t stream)
{
  const float* x     = (const float*)d_in[0];
  const float* ea    = (const float*)d_in[1];
  const int* nedges  = (const int*)d_in[2];
  const int* enodes  = (const int*)d_in[3];
  const float* Wlin  = (const float*)d_in[4];
  const float* Wedge = (const float*)d_in[5];
  const float* Wq    = (const float*)d_in[6];
  const float* Wk    = (const float*)d_in[7];
  const float* Wv    = (const float*)d_in[8];
  const float* bq    = (const float*)d_in[9];
  const float* bk    = (const float*)d_in[10];
  const float* bv    = (const float*)d_in[11];
  const float* Wo    = (const float*)d_in[12];
  const float* bo    = (const float*)d_in[13];
  float* out = (float*)d_out;

  unsigned short* wsp = (unsigned short*)d_ws;
  unsigned short* CW   = wsp;  wsp += 384 * 128;
  unsigned short* CWE  = wsp;  wsp += 128 * 64;
  unsigned short* Wob  = wsp;  wsp += 128 * 128;
  unsigned short* qb   = wsp;  wsp += (size_t)N_NODES * DIM;
  unsigned short* Kb   = wsp;  wsp += (size_t)N_NODES * DIM;
  unsigned short* Vb   = wsp;  wsp += (size_t)N_NODES * DIM;
  unsigned short* WeKb = wsp;  wsp += (size_t)N_EDGES * DIM;
  unsigned short* ctxb = wsp;  wsp += (size_t)N_NODES * DIM;

  wprep_kernel<<<dim3(288), dim3(256), 0, stream>>>(Wq, Wk, Wv, Wlin, Wedge, Wo, CW, CWE, Wob);
  g1_kernel<<<dim3(512, 6), dim3(256), 0, stream>>>(x, CW, bq, bv, qb, Kb, Vb);
  g2_kernel<<<dim3(256, 2), dim3(256), 0, stream>>>(ea, CWE, bk, WeKb);
  attn_kernel<<<dim3(8192), dim3(256), 0, stream>>>(qb, Kb, Vb, WeKb, nedges, enodes, ctxb);
  g4_kernel<<<dim3(512, 2), dim3(256), 0, stream>>>(ctxb, Wob, bo, out);
}

// Round 2
// 230.683 us; speedup vs baseline: 1.0562x; 1.0562x over previous
//
#include <hip/hip_runtime.h>

#define N_NODES 32768
#define N_EDGES 16384
#define DEG 4
#define KPE 8
#define DIM 128
#define EDIM 64

typedef float f32x4 __attribute__((ext_vector_type(4)));
typedef __bf16 bf16x8 __attribute__((ext_vector_type(8)));
typedef __bf16 bf16x2 __attribute__((ext_vector_type(2)));
typedef unsigned short u16x8 __attribute__((ext_vector_type(8)));

static __device__ __forceinline__ unsigned short f2bf(float f) {
  union { float f; unsigned int u; } v; v.f = f;
  unsigned int r = (v.u + 0x7FFFu + ((v.u >> 16) & 1u)) >> 16;
  return (unsigned short)r;
}
static __device__ __forceinline__ float bflo(unsigned int v) {
  union { unsigned int u; float f; } x; x.u = v << 16; return x.f;
}
static __device__ __forceinline__ float bfhi(unsigned int v) {
  union { unsigned int u; float f; } x; x.u = v & 0xffff0000u; return x.f;
}

#if __has_builtin(__builtin_amdgcn_fdot2_f32_bf16)
static __device__ __forceinline__ float dot2bf(unsigned int a, unsigned int b, float c) {
  return __builtin_amdgcn_fdot2_f32_bf16(
      __builtin_bit_cast(bf16x2, a), __builtin_bit_cast(bf16x2, b), c, false);
}
#else
static __device__ __forceinline__ float dot2bf(unsigned int a, unsigned int b, float c) {
  c = fmaf(bflo(a), bflo(b), c);
  return fmaf(bfhi(a), bfhi(b), c);
}
#endif

// ---------------- weight combine: CW=[0.25*Wq@Wlin; Wk@Wlin; Wv@Wlin] (384x128),
// CWE = Wk@Wedge (128x64), Wob = bf16(Wo) ----------------
__global__ __launch_bounds__(256) void wprep_kernel(
    const float* __restrict__ Wq, const float* __restrict__ Wk,
    const float* __restrict__ Wv, const float* __restrict__ Wlin,
    const float* __restrict__ Wedge, const float* __restrict__ Wo,
    unsigned short* __restrict__ CW, unsigned short* __restrict__ CWE,
    unsigned short* __restrict__ Wob)
{
  int id = blockIdx.x * 256 + threadIdx.x;
  if (id < 384 * 128) {
    int j = id >> 7, i = id & 127;
    const float* wrow; float scale = 1.0f;
    if (j < 128)      { wrow = Wq + j * 128; scale = 0.25f; }
    else if (j < 256) { wrow = Wk + (j - 128) * 128; }
    else              { wrow = Wv + (j - 256) * 128; }
    float s = 0.f;
    #pragma unroll 8
    for (int m = 0; m < 128; ++m) s += wrow[m] * Wlin[m * 128 + i];
    CW[id] = f2bf(s * scale);
  } else if (id < 384 * 128 + 128 * 64) {
    int id2 = id - 384 * 128; int j = id2 >> 6, t = id2 & 63;
    float s = 0.f;
    #pragma unroll 8
    for (int m = 0; m < 128; ++m) s += Wk[j * 128 + m] * Wedge[m * 64 + t];
    CWE[id2] = f2bf(s);
  } else if (id < 384 * 128 + 128 * 64 + 128 * 128) {
    int id3 = id - (384 * 128 + 128 * 64);
    Wob[id3] = f2bf(Wo[id3]);
  }
}

// ---------------- G1: x[N,128] @ CW[384,128]^T -> qb / WhKb / WhVb (bf16) ------
// x read & converted ONCE per block; 6 output col-groups looped internally.
__global__ __launch_bounds__(256) void g1_kernel(
    const float* __restrict__ x, const unsigned short* __restrict__ CW,
    const float* __restrict__ bq, const float* __restrict__ bv,
    unsigned short* __restrict__ qb, unsigned short* __restrict__ Kb,
    unsigned short* __restrict__ Vb)
{
  const int wave = threadIdx.x >> 6, lane = threadIdx.x & 63;
  const int r16 = lane & 15, quad = lane >> 4;
  const int m0 = blockIdx.x * 64 + wave * 16;

  u16x8 av[4];
  const float* arow = x + (size_t)(m0 + r16) * DIM + quad * 8;
  #pragma unroll
  for (int kk = 0; kk < 4; ++kk) {
    float4 a0 = *(const float4*)(arow + kk * 32);
    float4 a1 = *(const float4*)(arow + kk * 32 + 4);
    u16x8 au;
    au[0] = f2bf(a0.x); au[1] = f2bf(a0.y); au[2] = f2bf(a0.z); au[3] = f2bf(a0.w);
    au[4] = f2bf(a1.x); au[5] = f2bf(a1.y); au[6] = f2bf(a1.z); au[7] = f2bf(a1.w);
    av[kk] = au;
  }

  #pragma unroll
  for (int g = 0; g < 6; ++g) {
    f32x4 acc[4];
    const f32x4 z = {0.f, 0.f, 0.f, 0.f};
    acc[0] = z; acc[1] = z; acc[2] = z; acc[3] = z;
    #pragma unroll
    for (int kk = 0; kk < 4; ++kk) {
      #pragma unroll
      for (int s = 0; s < 4; ++s) {
        u16x8 bu = *(const u16x8*)(CW + (size_t)(g * 64 + s * 16 + r16) * DIM + kk * 32 + quad * 8);
        acc[s] = __builtin_amdgcn_mfma_f32_16x16x32_bf16(
            __builtin_bit_cast(bf16x8, av[kk]), __builtin_bit_cast(bf16x8, bu), acc[s], 0, 0, 0);
      }
    }
    const int arr = g >> 1;               // 0:q 1:K 2:V
    const int colbase = (g & 1) * 64;
    unsigned short* dst = arr == 0 ? qb : (arr == 1 ? Kb : Vb);
    #pragma unroll
    for (int s = 0; s < 4; ++s) {
      int j = colbase + s * 16 + r16;
      float bias = arr == 0 ? 0.25f * bq[j] : (arr == 2 ? bv[j] : 0.f);
      #pragma unroll
      for (int r = 0; r < 4; ++r) {
        int m = m0 + quad * 4 + r;
        dst[(size_t)m * DIM + j] = f2bf(acc[s][r] + bias);
      }
    }
  }
}

// ---------------- G2: edge_attr[E,64] @ CWE[128,64]^T + bk -> WeKb (bf16) ------
__global__ __launch_bounds__(256) void g2_kernel(
    const float* __restrict__ ea, const unsigned short* __restrict__ CWE,
    const float* __restrict__ bk, unsigned short* __restrict__ WeKb)
{
  const int wave = threadIdx.x >> 6, lane = threadIdx.x & 63;
  const int r16 = lane & 15, quad = lane >> 4;
  const int m0 = blockIdx.x * 64 + wave * 16;
  const int n0 = blockIdx.y * 64;

  f32x4 acc[4];
  const f32x4 z = {0.f, 0.f, 0.f, 0.f};
  acc[0] = z; acc[1] = z; acc[2] = z; acc[3] = z;

  const float* arow = ea + (size_t)(m0 + r16) * EDIM + quad * 8;
  #pragma unroll
  for (int kk = 0; kk < 2; ++kk) {
    float4 a0 = *(const float4*)(arow + kk * 32);
    float4 a1 = *(const float4*)(arow + kk * 32 + 4);
    u16x8 au;
    au[0] = f2bf(a0.x); au[1] = f2bf(a0.y); au[2] = f2bf(a0.z); au[3] = f2bf(a0.w);
    au[4] = f2bf(a1.x); au[5] = f2bf(a1.y); au[6] = f2bf(a1.z); au[7] = f2bf(a1.w);
    bf16x8 av = __builtin_bit_cast(bf16x8, au);
    #pragma unroll
    for (int s = 0; s < 4; ++s) {
      u16x8 bu = *(const u16x8*)(CWE + (size_t)(n0 + s * 16 + r16) * EDIM + kk * 32 + quad * 8);
      acc[s] = __builtin_amdgcn_mfma_f32_16x16x32_bf16(
          av, __builtin_bit_cast(bf16x8, bu), acc[s], 0, 0, 0);
    }
  }

  #pragma unroll
  for (int s = 0; s < 4; ++s) {
    int j = n0 + s * 16 + r16;
    float bias = bk[j];
    #pragma unroll
    for (int r = 0; r < 4; ++r) {
      int m = m0 + quad * 4 + r;
      WeKb[(size_t)m * DIM + j] = f2bf(acc[s][r] + bias);
    }
  }
}

// ---------------- G3: per-node attention (1 wave = 1 node) ----------------
// Full upfront prefetch: index loads (broadcast) -> q -> K gathers -> V gathers,
// in that issue order so in-order vmcnt retirement never forces a drain of the
// younger V loads when consuming K. One barrier (P redistribution via LDS).
__global__ __launch_bounds__(256) void attn_kernel(
    const unsigned short* __restrict__ qb, const unsigned short* __restrict__ Kb,
    const unsigned short* __restrict__ Vb, const unsigned short* __restrict__ WeKb,
    const int* __restrict__ nedges, const int* __restrict__ enodes,
    unsigned short* __restrict__ ctxb)
{
  __shared__ __align__(16) float ldsP[4][288];   // 8 heads x stride 36
  const int wave = threadIdx.x >> 6, lane = threadIdx.x & 63;
  const int n = blockIdx.x * 4 + wave;
  const int l = lane & 31, half = lane >> 5;
  const int j = l >> 3, lo8 = l & 7;
  const int c0 = lane * 2;                        // ctx dim pair
  const int h = lane >> 3;                        // ctx head

  // --- index loads (all wave-uniform addresses -> broadcast, L1) ---
  int4 e4 = *(const int4*)(nedges + (size_t)n * DEG);
  int e = (j & 2) ? ((j & 1) ? e4.w : e4.z) : ((j & 1) ? e4.y : e4.x);
  int u = enodes[(size_t)e * KPE + lo8];          // this lane's key node

  int uu[32];
  *(int4*)&uu[0]  = *(const int4*)(enodes + (size_t)e4.x * KPE);
  *(int4*)&uu[4]  = *(const int4*)(enodes + (size_t)e4.x * KPE + 4);
  *(int4*)&uu[8]  = *(const int4*)(enodes + (size_t)e4.y * KPE);
  *(int4*)&uu[12] = *(const int4*)(enodes + (size_t)e4.y * KPE + 4);
  *(int4*)&uu[16] = *(const int4*)(enodes + (size_t)e4.z * KPE);
  *(int4*)&uu[20] = *(const int4*)(enodes + (size_t)e4.z * KPE + 4);
  *(int4*)&uu[24] = *(const int4*)(enodes + (size_t)e4.w * KPE);
  *(int4*)&uu[28] = *(const int4*)(enodes + (size_t)e4.w * KPE + 4);

  // --- bulk prefetch: q, K-row, WeK-row, V-columns ---
  const uint4* qp = (const uint4*)(qb + (size_t)n * DIM + half * 64);
  const uint4* kp = (const uint4*)(Kb + (size_t)u * DIM + half * 64);
  const uint4* ep = (const uint4*)(WeKb + (size_t)e * DIM + half * 64);

  uint4 qv[8], kv[8], ev[8];
  #pragma unroll
  for (int ch = 0; ch < 8; ++ch) qv[ch] = qp[ch];
  #pragma unroll
  for (int ch = 0; ch < 8; ++ch) kv[ch] = kp[ch];
  #pragma unroll
  for (int ch = 0; ch < 8; ++ch) ev[ch] = ep[ch];

  unsigned int vv[32];
  #pragma unroll
  for (int t = 0; t < 32; ++t)
    vv[t] = *(const unsigned int*)(Vb + (size_t)uu[t] * DIM + c0);

  // --- scores: s[hi] = q . (K[u] + WeK[e]) over this half's 64 dims ---
  float s[4] = {0.f, 0.f, 0.f, 0.f};
  #pragma unroll
  for (int ch = 0; ch < 8; ++ch) {
    const int hi = ch >> 1;
    float t = s[hi];
    t = dot2bf(qv[ch].x, kv[ch].x, t); t = dot2bf(qv[ch].x, ev[ch].x, t);
    t = dot2bf(qv[ch].y, kv[ch].y, t); t = dot2bf(qv[ch].y, ev[ch].y, t);
    t = dot2bf(qv[ch].z, kv[ch].z, t); t = dot2bf(qv[ch].z, ev[ch].z, t);
    t = dot2bf(qv[ch].w, kv[ch].w, t); t = dot2bf(qv[ch].w, ev[ch].w, t);
    s[hi] = t;
  }

  // --- softmax over the 32 keys (within each 32-lane half-group) ---
  #pragma unroll
  for (int hi = 0; hi < 4; ++hi) {
    float vmax = s[hi];
    #pragma unroll
    for (int off = 16; off >= 1; off >>= 1)
      vmax = fmaxf(vmax, __shfl_xor(vmax, off, 32));
    float ex = __expf(s[hi] - vmax);
    float sum = ex;
    #pragma unroll
    for (int off = 16; off >= 1; off >>= 1)
      sum += __shfl_xor(sum, off, 32);
    ldsP[wave][(half * 4 + hi) * 36 + l] = ex / sum;
  }
  __syncthreads();

  // --- ctx: lane = dim pair, V already in registers, P via float4 LDS reads ---
  float a0 = 0.f, a1 = 0.f;
  #pragma unroll
  for (int t = 0; t < 8; ++t) {
    float4 p4 = *(const float4*)&ldsP[wave][h * 36 + t * 4];
    a0 = fmaf(p4.x, bflo(vv[t * 4 + 0]), a0); a1 = fmaf(p4.x, bfhi(vv[t * 4 + 0]), a1);
    a0 = fmaf(p4.y, bflo(vv[t * 4 + 1]), a0); a1 = fmaf(p4.y, bfhi(vv[t * 4 + 1]), a1);
    a0 = fmaf(p4.z, bflo(vv[t * 4 + 2]), a0); a1 = fmaf(p4.z, bfhi(vv[t * 4 + 2]), a1);
    a0 = fmaf(p4.w, bflo(vv[t * 4 + 3]), a0); a1 = fmaf(p4.w, bfhi(vv[t * 4 + 3]), a1);
  }
  unsigned int pk = (unsigned int)f2bf(a0) | ((unsigned int)f2bf(a1) << 16);
  *(unsigned int*)(ctxb + (size_t)n * DIM + c0) = pk;
}

// ---------------- G4: ctx[N,128] @ Wo[128,128]^T + bo, ReLU -> out fp32 -------
__global__ __launch_bounds__(256) void g4_kernel(
    const unsigned short* __restrict__ ctxb, const unsigned short* __restrict__ Wob,
    const float* __restrict__ bo, float* __restrict__ out)
{
  const int wave = threadIdx.x >> 6, lane = threadIdx.x & 63;
  const int r16 = lane & 15, quad = lane >> 4;
  const int m0 = blockIdx.x * 64 + wave * 16;
  const int n0 = blockIdx.y * 64;

  f32x4 acc[4];
  const f32x4 z = {0.f, 0.f, 0.f, 0.f};
  acc[0] = z; acc[1] = z; acc[2] = z; acc[3] = z;

  #pragma unroll
  for (int kk = 0; kk < 4; ++kk) {
    u16x8 au = *(const u16x8*)(ctxb + (size_t)(m0 + r16) * DIM + kk * 32 + quad * 8);
    bf16x8 av = __builtin_bit_cast(bf16x8, au);
    #pragma unroll
    for (int s = 0; s < 4; ++s) {
      u16x8 bu = *(const u16x8*)(Wob + (size_t)(n0 + s * 16 + r16) * DIM + kk * 32 + quad * 8);
      acc[s] = __builtin_amdgcn_mfma_f32_16x16x32_bf16(
          av, __builtin_bit_cast(bf16x8, bu), acc[s], 0, 0, 0);
    }
  }

  #pragma unroll
  for (int s = 0; s < 4; ++s) {
    int j = n0 + s * 16 + r16;
    float bias = bo[j];
    #pragma unroll
    for (int r = 0; r < 4; ++r) {
      int m = m0 + quad * 4 + r;
      float v = acc[s][r] + bias;
      out[(size_t)m * DIM + j] = v > 0.f ? v : 0.f;
    }
  }
}

extern "C" void kernel_launch(void* const* d_in, const int* in_sizes, int n_in,
                              void* d_out, int out_size, void* d_ws, size_t ws_size,
                              hipStream_t stream)
{
  const float* x     = (const float*)d_in[0];
  const float* ea    = (const float*)d_in[1];
  const int* nedges  = (const int*)d_in[2];
  const int* enodes  = (const int*)d_in[3];
  const float* Wlin  = (const float*)d_in[4];
  const float* Wedge = (const float*)d_in[5];
  const float* Wq    = (const float*)d_in[6];
  const float* Wk    = (const float*)d_in[7];
  const float* Wv    = (const float*)d_in[8];
  const float* bq    = (const float*)d_in[9];
  const float* bk    = (const float*)d_in[10];
  const float* bv    = (const float*)d_in[11];
  const float* Wo    = (const float*)d_in[12];
  const float* bo    = (const float*)d_in[13];
  float* out = (float*)d_out;

  unsigned short* wsp = (unsigned short*)d_ws;
  unsigned short* CW   = wsp;  wsp += 384 * 128;
  unsigned short* CWE  = wsp;  wsp += 128 * 64;
  unsigned short* Wob  = wsp;  wsp += 128 * 128;
  unsigned short* qb   = wsp;  wsp += (size_t)N_NODES * DIM;
  unsigned short* Kb   = wsp;  wsp += (size_t)N_NODES * DIM;
  unsigned short* Vb   = wsp;  wsp += (size_t)N_NODES * DIM;
  unsigned short* WeKb = wsp;  wsp += (size_t)N_EDGES * DIM;
  unsigned short* ctxb = wsp;  wsp += (size_t)N_NODES * DIM;

  wprep_kernel<<<dim3(288), dim3(256), 0, stream>>>(Wq, Wk, Wv, Wlin, Wedge, Wo, CW, CWE, Wob);
  g1_kernel<<<dim3(512), dim3(256), 0, stream>>>(x, CW, bq, bv, qb, Kb, Vb);
  g2_kernel<<<dim3(256, 2), dim3(256), 0, stream>>>(ea, CWE, bk, WeKb);
  attn_kernel<<<dim3(8192), dim3(256), 0, stream>>>(qb, Kb, Vb, WeKb, nedges, enodes, ctxb);
  g4_kernel<<<dim3(512, 2), dim3(256), 0, stream>>>(ctxb, Wob, bo, out);
}

// Round 3
// 215.467 us; speedup vs baseline: 1.1308x; 1.0706x over previous
//
#include <hip/hip_runtime.h>

#define N_NODES 32768
#define N_EDGES 16384
#define DEG 4
#define KPE 8
#define DIM 128
#define EDIM 64

typedef float f32x4 __attribute__((ext_vector_type(4)));
typedef __bf16 bf16x8 __attribute__((ext_vector_type(8)));
typedef __bf16 bf16x2 __attribute__((ext_vector_type(2)));
typedef unsigned short u16x8 __attribute__((ext_vector_type(8)));
typedef unsigned int u32;

static __device__ __forceinline__ unsigned short f2bf(float f) {
  union { float f; unsigned int u; } v; v.f = f;
  unsigned int r = (v.u + 0x7FFFu + ((v.u >> 16) & 1u)) >> 16;
  return (unsigned short)r;
}
static __device__ __forceinline__ float bflo(unsigned int v) {
  union { unsigned int u; float f; } x; x.u = v << 16; return x.f;
}
static __device__ __forceinline__ float bfhi(unsigned int v) {
  union { unsigned int u; float f; } x; x.u = v & 0xffff0000u; return x.f;
}

#if __has_builtin(__builtin_amdgcn_fdot2_f32_bf16)
static __device__ __forceinline__ float dot2bf(unsigned int a, unsigned int b, float c) {
  return __builtin_amdgcn_fdot2_f32_bf16(
      __builtin_bit_cast(bf16x2, a), __builtin_bit_cast(bf16x2, b), c, false);
}
#else
static __device__ __forceinline__ float dot2bf(unsigned int a, unsigned int b, float c) {
  c = fmaf(bflo(a), bflo(b), c);
  return fmaf(bfhi(a), bfhi(b), c);
}
#endif

// ---------------- weight combine: CW=[0.25*Wq@Wlin; Wk@Wlin; Wv@Wlin] (384x128),
// CWE = Wk@Wedge (128x64), Wob = bf16(Wo) ----------------
__global__ __launch_bounds__(256) void wprep_kernel(
    const float* __restrict__ Wq, const float* __restrict__ Wk,
    const float* __restrict__ Wv, const float* __restrict__ Wlin,
    const float* __restrict__ Wedge, const float* __restrict__ Wo,
    unsigned short* __restrict__ CW, unsigned short* __restrict__ CWE,
    unsigned short* __restrict__ Wob)
{
  int id = blockIdx.x * 256 + threadIdx.x;
  if (id < 384 * 128) {
    int j = id >> 7, i = id & 127;
    const float* wrow; float scale = 1.0f;
    if (j < 128)      { wrow = Wq + j * 128; scale = 0.25f; }
    else if (j < 256) { wrow = Wk + (j - 128) * 128; }
    else              { wrow = Wv + (j - 256) * 128; }
    float s = 0.f;
    #pragma unroll 8
    for (int m = 0; m < 128; ++m) s += wrow[m] * Wlin[m * 128 + i];
    CW[id] = f2bf(s * scale);
  } else if (id < 384 * 128 + 128 * 64) {
    int id2 = id - 384 * 128; int j = id2 >> 6, t = id2 & 63;
    float s = 0.f;
    #pragma unroll 8
    for (int m = 0; m < 128; ++m) s += Wk[j * 128 + m] * Wedge[m * 64 + t];
    CWE[id2] = f2bf(s);
  } else if (id < 384 * 128 + 128 * 64 + 128 * 128) {
    int id3 = id - (384 * 128 + 128 * 64);
    Wob[id3] = f2bf(Wo[id3]);
  }
}

// ---------------- G1: x[N,128] @ CW[384,128]^T -> qb / WhKb / WhVb (bf16) ------
__global__ __launch_bounds__(256) void g1_kernel(
    const float* __restrict__ x, const unsigned short* __restrict__ CW,
    const float* __restrict__ bq, const float* __restrict__ bv,
    unsigned short* __restrict__ qb, unsigned short* __restrict__ Kb,
    unsigned short* __restrict__ Vb)
{
  const int wave = threadIdx.x >> 6, lane = threadIdx.x & 63;
  const int r16 = lane & 15, quad = lane >> 4;
  const int m0 = blockIdx.x * 64 + wave * 16;

  u16x8 av[4];
  const float* arow = x + (size_t)(m0 + r16) * DIM + quad * 8;
  #pragma unroll
  for (int kk = 0; kk < 4; ++kk) {
    float4 a0 = *(const float4*)(arow + kk * 32);
    float4 a1 = *(const float4*)(arow + kk * 32 + 4);
    u16x8 au;
    au[0] = f2bf(a0.x); au[1] = f2bf(a0.y); au[2] = f2bf(a0.z); au[3] = f2bf(a0.w);
    au[4] = f2bf(a1.x); au[5] = f2bf(a1.y); au[6] = f2bf(a1.z); au[7] = f2bf(a1.w);
    av[kk] = au;
  }

  #pragma unroll
  for (int g = 0; g < 6; ++g) {
    f32x4 acc[4];
    const f32x4 z = {0.f, 0.f, 0.f, 0.f};
    acc[0] = z; acc[1] = z; acc[2] = z; acc[3] = z;
    #pragma unroll
    for (int kk = 0; kk < 4; ++kk) {
      #pragma unroll
      for (int s = 0; s < 4; ++s) {
        u16x8 bu = *(const u16x8*)(CW + (size_t)(g * 64 + s * 16 + r16) * DIM + kk * 32 + quad * 8);
        acc[s] = __builtin_amdgcn_mfma_f32_16x16x32_bf16(
            __builtin_bit_cast(bf16x8, av[kk]), __builtin_bit_cast(bf16x8, bu), acc[s], 0, 0, 0);
      }
    }
    const int arr = g >> 1;               // 0:q 1:K 2:V
    const int colbase = (g & 1) * 64;
    unsigned short* dst = arr == 0 ? qb : (arr == 1 ? Kb : Vb);
    #pragma unroll
    for (int s = 0; s < 4; ++s) {
      int j = colbase + s * 16 + r16;
      float bias = arr == 0 ? 0.25f * bq[j] : (arr == 2 ? bv[j] : 0.f);
      #pragma unroll
      for (int r = 0; r < 4; ++r) {
        int m = m0 + quad * 4 + r;
        dst[(size_t)m * DIM + j] = f2bf(acc[s][r] + bias);
      }
    }
  }
}

// ---------------- G2: edge_attr[E,64] @ CWE[128,64]^T + bk -> WeKb (bf16) ------
__global__ __launch_bounds__(256) void g2_kernel(
    const float* __restrict__ ea, const unsigned short* __restrict__ CWE,
    const float* __restrict__ bk, unsigned short* __restrict__ WeKb)
{
  const int wave = threadIdx.x >> 6, lane = threadIdx.x & 63;
  const int r16 = lane & 15, quad = lane >> 4;
  const int m0 = blockIdx.x * 64 + wave * 16;
  const int n0 = blockIdx.y * 64;

  f32x4 acc[4];
  const f32x4 z = {0.f, 0.f, 0.f, 0.f};
  acc[0] = z; acc[1] = z; acc[2] = z; acc[3] = z;

  const float* arow = ea + (size_t)(m0 + r16) * EDIM + quad * 8;
  #pragma unroll
  for (int kk = 0; kk < 2; ++kk) {
    float4 a0 = *(const float4*)(arow + kk * 32);
    float4 a1 = *(const float4*)(arow + kk * 32 + 4);
    u16x8 au;
    au[0] = f2bf(a0.x); au[1] = f2bf(a0.y); au[2] = f2bf(a0.z); au[3] = f2bf(a0.w);
    au[4] = f2bf(a1.x); au[5] = f2bf(a1.y); au[6] = f2bf(a1.z); au[7] = f2bf(a1.w);
    bf16x8 av = __builtin_bit_cast(bf16x8, au);
    #pragma unroll
    for (int s = 0; s < 4; ++s) {
      u16x8 bu = *(const u16x8*)(CWE + (size_t)(n0 + s * 16 + r16) * EDIM + kk * 32 + quad * 8);
      acc[s] = __builtin_amdgcn_mfma_f32_16x16x32_bf16(
          av, __builtin_bit_cast(bf16x8, bu), acc[s], 0, 0, 0);
    }
  }

  #pragma unroll
  for (int s = 0; s < 4; ++s) {
    int j = n0 + s * 16 + r16;
    float bias = bk[j];
    #pragma unroll
    for (int r = 0; r < 4; ++r) {
      int m = m0 + quad * 4 + r;
      WeKb[(size_t)m * DIM + j] = f2bf(acc[s][r] + bias);
    }
  }
}

// ---------------- G3: per-node attention (1 block = 1 wave = 1 node) ----------
// MLP-maximized: q/K/WeK prefetched into regs (launch_bounds(64,2) -> 256 VGPR
// budget so the compiler cannot sink the loads), V rows streamed into LDS via
// global_load_lds (zero VGPR cost, stays in flight across score+softmax).
// The P-exchange __syncthreads() doubles as the vmcnt(0) fence for the V DMA.
__global__ __launch_bounds__(64, 2) void attn_kernel(
    const unsigned short* __restrict__ qb, const unsigned short* __restrict__ Kb,
    const unsigned short* __restrict__ Vb, const unsigned short* __restrict__ WeKb,
    const int* __restrict__ nedges, const int* __restrict__ enodes,
    unsigned short* __restrict__ ctxb)
{
  __shared__ __align__(16) unsigned short ldsV[32][128];  // 8 KB: 32 V rows
  __shared__ __align__(16) float ldsP[8][36];             // P, padded stride
  const int lane = threadIdx.x;
  const int n = blockIdx.x;
  const int l = lane & 31, half = lane >> 5;
  const int j = l >> 3, lo8 = l & 7;
  const int c0 = lane * 2;                                 // ctx dim pair
  const int h = lane >> 3;                                 // ctx head

  // --- indices (wave-uniform broadcast loads) ---
  int4 e4 = *(const int4*)(nedges + (size_t)n * DEG);
  int e = (j & 2) ? ((j & 1) ? e4.w : e4.z) : ((j & 1) ? e4.y : e4.x);
  int u = enodes[(size_t)e * KPE + lo8];                   // this lane's key node

  int4 m0 = *(const int4*)(enodes + (size_t)e4.x * KPE);
  int4 m1 = *(const int4*)(enodes + (size_t)e4.x * KPE + 4);
  int4 m2 = *(const int4*)(enodes + (size_t)e4.y * KPE);
  int4 m3 = *(const int4*)(enodes + (size_t)e4.y * KPE + 4);
  int4 m4 = *(const int4*)(enodes + (size_t)e4.z * KPE);
  int4 m5 = *(const int4*)(enodes + (size_t)e4.z * KPE + 4);
  int4 m6 = *(const int4*)(enodes + (size_t)e4.w * KPE);
  int4 m7 = *(const int4*)(enodes + (size_t)e4.w * KPE + 4);

  // --- register prefetch: q, K-row-half, WeK-row-half (issue order = use order)
  const uint4* qp = (const uint4*)(qb + (size_t)n * DIM + half * 64);
  const uint4* kp = (const uint4*)(Kb + (size_t)u * DIM + half * 64);
  const uint4* ep = (const uint4*)(WeKb + (size_t)e * DIM + half * 64);
  uint4 qv[8], kv[8], ev[8];
  #pragma unroll
  for (int ch = 0; ch < 8; ++ch) qv[ch] = qp[ch];
  #pragma unroll
  for (int ch = 0; ch < 8; ++ch) kv[ch] = kp[ch];
  #pragma unroll
  for (int ch = 0; ch < 8; ++ch) ev[ch] = ep[ch];

  // --- V rows -> LDS via async DMA (one instr stages one full 256 B row) ---
#define STAGE_V(t, node) do {                                                   \
    const u32* gp_ = (const u32*)(Vb + (size_t)(node) * DIM) + lane;            \
    __builtin_amdgcn_global_load_lds(                                           \
        (const __attribute__((address_space(1))) u32*)gp_,                      \
        (__attribute__((address_space(3))) u32*)&ldsV[t][0], 4, 0, 0);          \
  } while (0)
  STAGE_V(0,  m0.x); STAGE_V(1,  m0.y); STAGE_V(2,  m0.z); STAGE_V(3,  m0.w);
  STAGE_V(4,  m1.x); STAGE_V(5,  m1.y); STAGE_V(6,  m1.z); STAGE_V(7,  m1.w);
  STAGE_V(8,  m2.x); STAGE_V(9,  m2.y); STAGE_V(10, m2.z); STAGE_V(11, m2.w);
  STAGE_V(12, m3.x); STAGE_V(13, m3.y); STAGE_V(14, m3.z); STAGE_V(15, m3.w);
  STAGE_V(16, m4.x); STAGE_V(17, m4.y); STAGE_V(18, m4.z); STAGE_V(19, m4.w);
  STAGE_V(20, m5.x); STAGE_V(21, m5.y); STAGE_V(22, m5.z); STAGE_V(23, m5.w);
  STAGE_V(24, m6.x); STAGE_V(25, m6.y); STAGE_V(26, m6.z); STAGE_V(27, m6.w);
  STAGE_V(28, m7.x); STAGE_V(29, m7.y); STAGE_V(30, m7.z); STAGE_V(31, m7.w);
#undef STAGE_V

  // --- scores: s[hi] = q . (K[u] + WeK[e]) over this half's 64 dims ---
  float s[4] = {0.f, 0.f, 0.f, 0.f};
  #pragma unroll
  for (int ch = 0; ch < 8; ++ch) {
    const int hi = ch >> 1;
    float t = s[hi];
    t = dot2bf(qv[ch].x, kv[ch].x, t); t = dot2bf(qv[ch].x, ev[ch].x, t);
    t = dot2bf(qv[ch].y, kv[ch].y, t); t = dot2bf(qv[ch].y, ev[ch].y, t);
    t = dot2bf(qv[ch].z, kv[ch].z, t); t = dot2bf(qv[ch].z, ev[ch].z, t);
    t = dot2bf(qv[ch].w, kv[ch].w, t); t = dot2bf(qv[ch].w, ev[ch].w, t);
    s[hi] = t;
  }

  // --- softmax over the 32 keys (within each 32-lane half-group) ---
  #pragma unroll
  for (int hi = 0; hi < 4; ++hi) {
    float vmax = s[hi];
    #pragma unroll
    for (int off = 16; off >= 1; off >>= 1)
      vmax = fmaxf(vmax, __shfl_xor(vmax, off, 32));
    float ex = __expf(s[hi] - vmax);
    float sum = ex;
    #pragma unroll
    for (int off = 16; off >= 1; off >>= 1)
      sum += __shfl_xor(sum, off, 32);
    ldsP[half * 4 + hi][l] = ex / sum;
  }
  __syncthreads();   // drains vmcnt(0): V rows staged, P visible

  // --- ctx: lane = dim pair; V from LDS (bank = lane%32, 2-way = free) ---
  float a0 = 0.f, a1 = 0.f;
  #pragma unroll
  for (int t = 0; t < 8; ++t) {
    float4 p4 = *(const float4*)&ldsP[h][t * 4];
    u32 v0 = *(const u32*)&ldsV[t * 4 + 0][c0];
    u32 v1 = *(const u32*)&ldsV[t * 4 + 1][c0];
    u32 v2 = *(const u32*)&ldsV[t * 4 + 2][c0];
    u32 v3 = *(const u32*)&ldsV[t * 4 + 3][c0];
    a0 = fmaf(p4.x, bflo(v0), a0); a1 = fmaf(p4.x, bfhi(v0), a1);
    a0 = fmaf(p4.y, bflo(v1), a0); a1 = fmaf(p4.y, bfhi(v1), a1);
    a0 = fmaf(p4.z, bflo(v2), a0); a1 = fmaf(p4.z, bfhi(v2), a1);
    a0 = fmaf(p4.w, bflo(v3), a0); a1 = fmaf(p4.w, bfhi(v3), a1);
  }
  unsigned int pk = (unsigned int)f2bf(a0) | ((unsigned int)f2bf(a1) << 16);
  *(unsigned int*)(ctxb + (size_t)n * DIM + c0) = pk;
}

// ---------------- G4: ctx[N,128] @ Wo[128,128]^T + bo, ReLU -> out fp32 -------
__global__ __launch_bounds__(256) void g4_kernel(
    const unsigned short* __restrict__ ctxb, const unsigned short* __restrict__ Wob,
    const float* __restrict__ bo, float* __restrict__ out)
{
  const int wave = threadIdx.x >> 6, lane = threadIdx.x & 63;
  const int r16 = lane & 15, quad = lane >> 4;
  const int m0 = blockIdx.x * 64 + wave * 16;
  const int n0 = blockIdx.y * 64;

  f32x4 acc[4];
  const f32x4 z = {0.f, 0.f, 0.f, 0.f};
  acc[0] = z; acc[1] = z; acc[2] = z; acc[3] = z;

  #pragma unroll
  for (int kk = 0; kk < 4; ++kk) {
    u16x8 au = *(const u16x8*)(ctxb + (size_t)(m0 + r16) * DIM + kk * 32 + quad * 8);
    bf16x8 av = __builtin_bit_cast(bf16x8, au);
    #pragma unroll
    for (int s = 0; s < 4; ++s) {
      u16x8 bu = *(const u16x8*)(Wob + (size_t)(n0 + s * 16 + r16) * DIM + kk * 32 + quad * 8);
      acc[s] = __builtin_amdgcn_mfma_f32_16x16x32_bf16(
          av, __builtin_bit_cast(bf16x8, bu), acc[s], 0, 0, 0);
    }
  }

  #pragma unroll
  for (int s = 0; s < 4; ++s) {
    int j = n0 + s * 16 + r16;
    float bias = bo[j];
    #pragma unroll
    for (int r = 0; r < 4; ++r) {
      int m = m0 + quad * 4 + r;
      float v = acc[s][r] + bias;
      out[(size_t)m * DIM + j] = v > 0.f ? v : 0.f;
    }
  }
}

extern "C" void kernel_launch(void* const* d_in, const int* in_sizes, int n_in,
                              void* d_out, int out_size, void* d_ws, size_t ws_size,
                              hipStream_t stream)
{
  const float* x     = (const float*)d_in[0];
  const float* ea    = (const float*)d_in[1];
  const int* nedges  = (const int*)d_in[2];
  const int* enodes  = (const int*)d_in[3];
  const float* Wlin  = (const float*)d_in[4];
  const float* Wedge = (const float*)d_in[5];
  const float* Wq    = (const float*)d_in[6];
  const float* Wk    = (const float*)d_in[7];
  const float* Wv    = (const float*)d_in[8];
  const float* bq    = (const float*)d_in[9];
  const float* bk    = (const float*)d_in[10];
  const float* bv    = (const float*)d_in[11];
  const float* Wo    = (const float*)d_in[12];
  const float* bo    = (const float*)d_in[13];
  float* out = (float*)d_out;

  unsigned short* wsp = (unsigned short*)d_ws;
  unsigned short* CW   = wsp;  wsp += 384 * 128;
  unsigned short* CWE  = wsp;  wsp += 128 * 64;
  unsigned short* Wob  = wsp;  wsp += 128 * 128;
  unsigned short* qb   = wsp;  wsp += (size_t)N_NODES * DIM;
  unsigned short* Kb   = wsp;  wsp += (size_t)N_NODES * DIM;
  unsigned short* Vb   = wsp;  wsp += (size_t)N_NODES * DIM;
  unsigned short* WeKb = wsp;  wsp += (size_t)N_EDGES * DIM;
  unsigned short* ctxb = wsp;  wsp += (size_t)N_NODES * DIM;

  wprep_kernel<<<dim3(288), dim3(256), 0, stream>>>(Wq, Wk, Wv, Wlin, Wedge, Wo, CW, CWE, Wob);
  g1_kernel<<<dim3(512), dim3(256), 0, stream>>>(x, CW, bq, bv, qb, Kb, Vb);
  g2_kernel<<<dim3(256, 2), dim3(256), 0, stream>>>(ea, CWE, bk, WeKb);
  attn_kernel<<<dim3(32768), dim3(64), 0, stream>>>(qb, Kb, Vb, WeKb, nedges, enodes, ctxb);
  g4_kernel<<<dim3(512, 2), dim3(256), 0, stream>>>(ctxb, Wob, bo, out);
}